// Round 3
// baseline (1388.308 us; speedup 1.0000x reference)
//
#include <hip/hip_runtime.h>
#include <hip/hip_bf16.h>

typedef _Float16 half8 __attribute__((ext_vector_type(8)));
typedef float f32x4 __attribute__((ext_vector_type(4)));

#define B_TOTAL 32768
#define T 7
#define F 36
#define U 256
#define G4 1024
#define BM 32
#define NTHREADS 512
#define KC 10          // K chunks of 32: kc 0..7 = h (K=256), kc 8..9 = x (F=36 pad 64)
#define KPACK 32
#define K_BIAS 316     // bias rides on constant-1.0 pad column (x index 60)
#define H_STRIDE 264   // halves; 528 B rows, 16B aligned
#define X_STRIDE 72    // halves; 144 B rows, 16B aligned

// Pack W = [Wr (k 0..255); Wk (k 256..291); bias (k 316); zeros] into
// fragment-native Wq[kc][n][kin] fp16: B-frag = one coalesced 16B load/lane.
__global__ __launch_bounds__(1024) void pack_w(const float* __restrict__ Wr,
                                               const float* __restrict__ Wk,
                                               const float* __restrict__ bias,
                                               _Float16* __restrict__ Wq) {
    const int kc   = blockIdx.x >> 2;
    const int kin0 = (blockIdx.x & 3) * 8;
    const int n    = threadIdx.x;
    _Float16* dst = Wq + ((size_t)kc * G4 + n) * KPACK + kin0;
    #pragma unroll
    for (int j = 0; j < 8; ++j) {
        int k = kc * KPACK + kin0 + j;
        float v = 0.f;
        if (k < U)            v = Wr[(size_t)k * G4 + n];
        else if (k < U + F)   v = Wk[(size_t)(k - U) * G4 + n];
        else if (k == K_BIAS) v = bias[n];
        dst[j] = (_Float16)v;
    }
}

__device__ __forceinline__ float fast_sigmoid(float x) {
    return __builtin_amdgcn_rcpf(1.f + __expf(-x));
}
__device__ __forceinline__ float fast_tanh(float x) {
    return 1.f - 2.f * __builtin_amdgcn_rcpf(1.f + __expf(2.f * x));
}

// Persistent LSTM: block = 512 threads (8 waves) owns BM=32 batch rows, all T steps.
// Wave w owns u-cols [32w, 32w+32) x 4 gates x 32 rows. 2 blocks resident/CU.
// Ping-pong LDS: ONE barrier per step.
__global__ __launch_bounds__(NTHREADS, 4) void lstm_kernel(
    const float* __restrict__ x,     // [B,T,F]
    const float* __restrict__ h0,    // [B,U]
    const float* __restrict__ c0,    // [B,U]
    const _Float16* __restrict__ Wq, // packed [KC][G4][KPACK]
    float* __restrict__ out)         // [B,T,U]
{
    __shared__ __align__(16) _Float16 hA[2][BM * H_STRIDE];
    __shared__ __align__(16) _Float16 xA[2][BM * X_STRIDE];

    const int tid  = threadIdx.x;
    const int lane = tid & 63;
    const int w    = tid >> 6;     // 0..7
    const int l15  = lane & 15;
    const int q    = lane >> 4;    // 0..3
    const int u0   = w * 32;
    const int b0   = blockIdx.x * BM;

    // --- stage h0 -> hA[0] (fp16) ---
    for (int i = tid; i < BM * U; i += NTHREADS) {
        int m = i >> 8, u = i & 255;
        hA[0][m * H_STRIDE + u] = (_Float16)h0[(size_t)b0 * U + i];
    }
    // --- init pad cols F..63 in BOTH x buffers: 1.0 at bias column, else 0 ---
    for (int i = tid; i < 2 * BM * (64 - F); i += NTHREADS) {
        int buf = i / (BM * (64 - F));
        int j   = i % (BM * (64 - F));
        int m = j / (64 - F), f = F + j % (64 - F);
        xA[buf][m * X_STRIDE + f] = (f == (K_BIAS - U)) ? (_Float16)1.f : (_Float16)0.f;
    }
    // --- stage x(t=0) -> xA[0] ---
    for (int i = tid; i < BM * F; i += NTHREADS) {
        int m = i / F, f = i % F;
        xA[0][m * X_STRIDE + f] = (_Float16)x[((size_t)(b0 + m) * T) * F + f];
    }
    // --- c0 into registers: c[mt][us][r] at row mt*16+q*4+r, col u0+us*16+l15 ---
    float c[16];
    #pragma unroll
    for (int mt = 0; mt < 2; ++mt)
        #pragma unroll
        for (int us = 0; us < 2; ++us)
            #pragma unroll
            for (int r = 0; r < 4; ++r) {
                int row = mt * 16 + q * 4 + r;
                c[(mt * 2 + us) * 4 + r] = c0[(size_t)(b0 + row) * U + u0 + us * 16 + l15];
            }

    __syncthreads();

    for (int t = 0; t < T; ++t) {
        const int p = t & 1;
        f32x4 acc[2][2][4];   // [mt][us][gate]; bias arrives via K_BIAS row
        #pragma unroll
        for (int mt = 0; mt < 2; ++mt)
            #pragma unroll
            for (int us = 0; us < 2; ++us)
                #pragma unroll
                for (int g = 0; g < 4; ++g)
                    acc[mt][us][g] = (f32x4){0.f, 0.f, 0.f, 0.f};

        // prefetch next x slice into regs (hidden under K-loop)
        float xp0 = 0.f, xp1 = 0.f, xp2 = 0.f;
        if (t + 1 < T) {
            { int i = tid;       int m = i / F, f = i % F;
              xp0 = x[((size_t)(b0 + m) * T + t + 1) * F + f]; }
            { int i = tid + 512; int m = i / F, f = i % F;
              xp1 = x[((size_t)(b0 + m) * T + t + 1) * F + f]; }
            if (tid < BM * F - 1024) {
                int i = tid + 1024; int m = i / F, f = i % F;
                xp2 = x[((size_t)(b0 + m) * T + t + 1) * F + f];
            }
        }

        // --- K loop: z[32,1024] = [h,x,1] @ Wq ---
        #pragma unroll
        for (int kc = 0; kc < KC; ++kc) {
            half8 af[2];
            if (kc < 8) {
                af[0] = *(const half8*)&hA[p][(l15)      * H_STRIDE + kc * 32 + q * 8];
                af[1] = *(const half8*)&hA[p][(16 + l15) * H_STRIDE + kc * 32 + q * 8];
            } else {
                af[0] = *(const half8*)&xA[p][(l15)      * X_STRIDE + (kc - 8) * 32 + q * 8];
                af[1] = *(const half8*)&xA[p][(16 + l15) * X_STRIDE + (kc - 8) * 32 + q * 8];
            }
            #pragma unroll
            for (int g = 0; g < 4; ++g) {
                half8 bf0 = *(const half8*)(Wq + ((size_t)kc * G4 + g * U + u0 + l15)      * KPACK + q * 8);
                half8 bf1 = *(const half8*)(Wq + ((size_t)kc * G4 + g * U + u0 + 16 + l15) * KPACK + q * 8);
                acc[0][0][g] = __builtin_amdgcn_mfma_f32_16x16x32_f16(af[0], bf0, acc[0][0][g], 0, 0, 0);
                acc[0][1][g] = __builtin_amdgcn_mfma_f32_16x16x32_f16(af[0], bf1, acc[0][1][g], 0, 0, 0);
                acc[1][0][g] = __builtin_amdgcn_mfma_f32_16x16x32_f16(af[1], bf0, acc[1][0][g], 0, 0, 0);
                acc[1][1][g] = __builtin_amdgcn_mfma_f32_16x16x32_f16(af[1], bf1, acc[1][1][g], 0, 0, 0);
            }
        }

        // --- gates: i,f,g,o for each (row,u) live in the same lane ---
        #pragma unroll
        for (int mt = 0; mt < 2; ++mt)
            #pragma unroll
            for (int us = 0; us < 2; ++us)
                #pragma unroll
                for (int r = 0; r < 4; ++r) {
                    int ci = (mt * 2 + us) * 4 + r;
                    float zi = acc[mt][us][0][r];
                    float zf = acc[mt][us][1][r];
                    float zg = acc[mt][us][2][r];
                    float zo = acc[mt][us][3][r];
                    float ig = fast_sigmoid(zi);
                    float fg = fast_sigmoid(zf);
                    float gg = fast_tanh(zg);
                    float og = fast_sigmoid(zo);
                    float cn = fg * c[ci] + ig * gg;
                    c[ci] = cn;
                    float hv = og * fast_tanh(cn);
                    int row = mt * 16 + q * 4 + r;
                    hA[p ^ 1][row * H_STRIDE + u0 + us * 16 + l15] = (_Float16)hv;
                }

        // stage prefetched x(t+1) -> xA[p^1] (pad cols already initialized)
        if (t + 1 < T) {
            { int i = tid;       int m = i / F, f = i % F; xA[p ^ 1][m * X_STRIDE + f] = (_Float16)xp0; }
            { int i = tid + 512; int m = i / F, f = i % F; xA[p ^ 1][m * X_STRIDE + f] = (_Float16)xp1; }
            if (tid < BM * F - 1024) {
                int i = tid + 1024; int m = i / F, f = i % F;
                xA[p ^ 1][m * X_STRIDE + f] = (_Float16)xp2;
            }
        }

        __syncthreads();   // orders: h/x writes -> readers; K-loop reads -> next writes

        // --- coalesced out-store of h_t from hA[p^1]: fire-and-forget,
        // overlaps next step's K-loop (both only READ hA[p^1]). ---
        #pragma unroll
        for (int rb = 0; rb < 2; ++rb) {
            int j   = tid + rb * NTHREADS;  // 0..1023 chunks of 8 floats
            int row = j >> 5;
            int uo  = (j & 31) * 8;
            half8 hv = *(const half8*)&hA[p ^ 1][row * H_STRIDE + uo];
            f32x4 lo = { (float)hv[0], (float)hv[1], (float)hv[2], (float)hv[3] };
            f32x4 hi = { (float)hv[4], (float)hv[5], (float)hv[6], (float)hv[7] };
            float* dst = out + ((size_t)(b0 + row) * T + t) * U + uo;
            *(f32x4*)dst       = lo;
            *(f32x4*)(dst + 4) = hi;
        }
    }
}

extern "C" void kernel_launch(void* const* d_in, const int* in_sizes, int n_in,
                              void* d_out, int out_size, void* d_ws, size_t ws_size,
                              hipStream_t stream) {
    const float* x  = (const float*)d_in[0];
    const float* h0 = (const float*)d_in[1];
    const float* c0 = (const float*)d_in[2];
    const float* Wk = (const float*)d_in[3];
    const float* Wr = (const float*)d_in[4];
    const float* b  = (const float*)d_in[5];
    float* out = (float*)d_out;

    _Float16* Wq = (_Float16*)d_ws;   // KC*G4*KPACK*2 = 640 KB

    pack_w<<<KC * 4, 1024, 0, stream>>>(Wr, Wk, b, Wq);
    lstm_kernel<<<B_TOTAL / BM, NTHREADS, 0, stream>>>(x, h0, c0, Wq, out);
}